// Round 14
// baseline (452.223 us; speedup 1.0000x reference)
//
#include <hip/hip_runtime.h>
#include <hip/hip_bf16.h>
#include <hip/hip_cooperative_groups.h>
#include <math.h>

namespace cg = cooperative_groups;

#define CAP 2048
#define PRNG_PARTITIONABLE 1

typedef __attribute__((ext_vector_type(8))) short bf16x8;
typedef __attribute__((ext_vector_type(4))) float f32x4;
typedef __attribute__((ext_vector_type(4))) unsigned int u32x4;

union B8U4 { u32x4 u; bf16x8 b; };

// LDS-only barrier (R13): drain LDS ops, NOT vmcnt.
#define BARRIER_LDS { asm volatile("s_waitcnt lgkmcnt(0)" ::: "memory"); \
                      __builtin_amdgcn_sched_barrier(0);                  \
                      __builtin_amdgcn_s_barrier(); }

// ---------- helpers ----------
__device__ __forceinline__ unsigned int f2ord(float x) {
  unsigned int u = __float_as_uint(x);
  return (u & 0x80000000u) ? ~u : (u | 0x80000000u);
}

__device__ __forceinline__ unsigned int rotl_u32(unsigned int x, int r) {
  return (x << r) | (x >> (32 - r));
}

__device__ float gumbel_at(unsigned int flat, unsigned int half_n) {
  const unsigned int ks0 = 0u;
  const unsigned int ks1 = 42u;
  const unsigned int ks2 = 0x1BD11BDAu ^ ks0 ^ ks1;
  unsigned int x0, x1;
#if PRNG_PARTITIONABLE
  x0 = 0u;
  x1 = flat;
#else
  unsigned int cnt = (flat < half_n) ? flat : (flat - half_n);
  x0 = cnt; x1 = cnt + half_n;
#endif
  x0 += ks0; x1 += ks1;
#define TF_R(r) { x0 += x1; x1 = rotl_u32(x1, r); x1 ^= x0; }
  TF_R(13) TF_R(15) TF_R(26) TF_R(6)
  x0 += ks1; x1 += ks2 + 1u;
  TF_R(17) TF_R(29) TF_R(16) TF_R(24)
  x0 += ks2; x1 += ks0 + 2u;
  TF_R(13) TF_R(15) TF_R(26) TF_R(6)
  x0 += ks0; x1 += ks1 + 3u;
  TF_R(17) TF_R(29) TF_R(16) TF_R(24)
  x0 += ks1; x1 += ks2 + 4u;
  TF_R(13) TF_R(15) TF_R(26) TF_R(6)
  x0 += ks2; x1 += ks0 + 5u;
#undef TF_R
#if PRNG_PARTITIONABLE
  unsigned int bits = x0 ^ x1;
#else
  unsigned int bits = (flat < half_n) ? x0 : x1;
#endif
  float f = __uint_as_float(0x3f800000u | (bits >> 9)) - 1.0f;
  float u = fmaxf(1e-20f, f + 1e-20f);
  return -logf(-logf(u));
}

__device__ __forceinline__ unsigned short f32_to_bf16_rne(float x) {
  unsigned int u = __float_as_uint(x);
  unsigned int r = u + 0x7fffu + ((u >> 16) & 1u);
  return (unsigned short)(r >> 16);
}
__device__ __forceinline__ float bf16u_to_f32(unsigned short h) {
  return __uint_as_float(((unsigned int)h) << 16);
}

struct HL { unsigned int h, l; };
__device__ __forceinline__ HL cvt_pair(float a, float b) {
  float2 xf = make_float2(a, b);
  __hip_bfloat162 hh = __float22bfloat162_rn(xf);
  float2 hf = __bfloat1622float2(hh);
  __hip_bfloat162 ll = __float22bfloat162_rn(make_float2(a - hf.x, b - hf.y));
  HL r;
  __builtin_memcpy(&r.h, &hh, 4);
  __builtin_memcpy(&r.l, &ll, 4);
  return r;
}

__device__ __forceinline__ f32x4 mfma16(bf16x8 a, bf16x8 b, f32x4 c) {
  return __builtin_amdgcn_mfma_f32_16x16x32_bf16(a, b, c, 0, 0, 0);
}

// ---------- K0: gather last-token rows + split to bf16 hi/lo ----------
__global__ void gather_split(const float* __restrict__ hidden, const int* __restrict__ lti,
                             unsigned short* __restrict__ Ah, unsigned short* __restrict__ Al,
                             int D) {
  int b = blockIdx.x;
  const float* src = hidden + (size_t)lti[b] * D;
  for (int i = threadIdx.x; i < D; i += blockDim.x) {
    float x = src[i];
    unsigned short h = f32_to_bf16_rne(x);
    float r = x - bf16u_to_f32(h);
    Ah[(size_t)b * D + i] = h;
    Al[(size_t)b * D + i] = f32_to_bf16_rne(r);
  }
}

// ---------- K1: logits = A @ E^T via bf16x3 MFMA (R13, 227us) ----------
#define BN 128
#define BK 64
__global__ __launch_bounds__(256) void gemm_mfma(
    const unsigned short* __restrict__ Ahg, const unsigned short* __restrict__ Alg,
    const float* __restrict__ E, float* __restrict__ outL, int D, int V) {
  __shared__ __align__(16) float BS[128 * 64];
  __shared__ __align__(16) unsigned short AhS[64 * 64];
  __shared__ __align__(16) unsigned short AlS[64 * 64];

  const int t = threadIdx.x;
  const int lane = t & 63;
  const int wv = t >> 6;
  const long n0 = (long)blockIdx.x * BN;
  const int am = t >> 2, ao = t & 3;

  f32x4 acc[4][2];
#pragma unroll
  for (int i = 0; i < 4; ++i)
#pragma unroll
    for (int j = 0; j < 2; ++j) acc[i][j] = (f32x4){0.f, 0.f, 0.f, 0.f};

  f32x4 bA[8], bB[8];
  bf16x8 aA[4], aB[4];

  auto LOAD = [&](f32x4* br, bf16x8* ar, int k0) {
#pragma unroll
    for (int q = 0; q < 4; ++q) {
      int gi = q * 256 + t, n = gi >> 3, o = gi & 7;
      const float* s = E + (size_t)(n0 + n) * D + k0 + o * 8;
      br[2 * q] = *(const f32x4*)s;
      br[2 * q + 1] = *(const f32x4*)(s + 4);
    }
    const unsigned short* ph = Ahg + (size_t)am * D + k0 + ao * 16;
    ar[0] = *(const bf16x8*)ph;
    ar[1] = *(const bf16x8*)(ph + 8);
    const unsigned short* pl = Alg + (size_t)am * D + k0 + ao * 16;
    ar[2] = *(const bf16x8*)pl;
    ar[3] = *(const bf16x8*)(pl + 8);
  };

  auto STAGE = [&](f32x4* br, bf16x8* ar) {
#pragma unroll
    for (int q = 0; q < 4; ++q) {
      int gi = q * 256 + t, n = gi >> 3, o = gi & 7;
      int pg0 = (2 * o) ^ (n & 7);
      int pg1 = (2 * o + 1) ^ (n & 7);
      *(f32x4*)&BS[n * 64 + pg0 * 4] = br[2 * q];
      *(f32x4*)&BS[n * 64 + pg1 * 4] = br[2 * q + 1];
    }
    int g0 = ao * 2;
    int off0 = am * 64 + ((g0 ^ (am & 7)) * 8);
    int off1 = am * 64 + (((g0 + 1) ^ (am & 7)) * 8);
    *(bf16x8*)&AhS[off0] = ar[0];
    *(bf16x8*)&AhS[off1] = ar[1];
    *(bf16x8*)&AlS[off0] = ar[2];
    *(bf16x8*)&AlS[off1] = ar[3];
  };

  auto COMPUTE = [&]() {
#pragma unroll
    for (int k32 = 0; k32 < 2; ++k32) {
      const int og = k32 * 4 + (lane >> 4);
      bf16x8 ah[4], al[4], bh[2], bl[2];
#pragma unroll
      for (int mf = 0; mf < 4; ++mf) {
        int r = mf * 16 + (lane & 15);
        int off = r * 64 + ((og ^ (r & 7)) * 8);
        ah[mf] = *(const bf16x8*)&AhS[off];
        al[mf] = *(const bf16x8*)&AlS[off];
      }
#pragma unroll
      for (int nf = 0; nf < 2; ++nf) {
        int n = wv * 32 + nf * 16 + (lane & 15);
        int pg0 = (2 * og) ^ (n & 7);
        int pg1 = (2 * og + 1) ^ (n & 7);
        f32x4 v0 = *(const f32x4*)&BS[n * 64 + pg0 * 4];
        f32x4 v1 = *(const f32x4*)&BS[n * 64 + pg1 * 4];
        HL p0 = cvt_pair(v0.x, v0.y);
        HL p1 = cvt_pair(v0.z, v0.w);
        HL p2 = cvt_pair(v1.x, v1.y);
        HL p3 = cvt_pair(v1.z, v1.w);
        B8U4 hb, lb;
        hb.u = (u32x4){p0.h, p1.h, p2.h, p3.h};
        lb.u = (u32x4){p0.l, p1.l, p2.l, p3.l};
        bh[nf] = hb.b;
        bl[nf] = lb.b;
      }
      __builtin_amdgcn_s_setprio(1);
#pragma unroll
      for (int mf = 0; mf < 4; ++mf)
#pragma unroll
        for (int nf = 0; nf < 2; ++nf) {
          acc[mf][nf] = mfma16(ah[mf], bh[nf], acc[mf][nf]);
          acc[mf][nf] = mfma16(ah[mf], bl[nf], acc[mf][nf]);
          acc[mf][nf] = mfma16(al[mf], bh[nf], acc[mf][nf]);
        }
      __builtin_amdgcn_s_setprio(0);
    }
  };

  LOAD(bA, aA, 0);
#pragma unroll 1
  for (int k0 = 0; k0 < D; k0 += 2 * BK) {
    if (k0 + BK < D) LOAD(bB, aB, k0 + BK);
    BARRIER_LDS;
    STAGE(bA, aA);
    BARRIER_LDS;
    COMPUTE();
    if (k0 + 2 * BK < D) LOAD(bA, aA, k0 + 2 * BK);
    BARRIER_LDS;
    STAGE(bB, aB);
    BARRIER_LDS;
    COMPUTE();
  }

#pragma unroll
  for (int mf = 0; mf < 4; ++mf)
#pragma unroll
    for (int nf = 0; nf < 2; ++nf) {
      long v = n0 + wv * 32 + nf * 16 + (lane & 15);
      int rbase = mf * 16 + ((lane >> 4) << 2);
#pragma unroll
      for (int reg = 0; reg < 4; ++reg)
        outL[(size_t)(rbase + reg) * V + v] = acc[mf][nf][reg];
    }
}

// ---------- K2: cooperative select — hist | sync | thresh | sync | gather ---
// grid = 8*B blocks x 256 threads. Slice-based hist: no memset, no atomics
// to global. Same integer arithmetic as R12/R13 split kernels.
__global__ __launch_bounds__(256) void select_coop(
    float* __restrict__ logits, const int* __restrict__ top_ks,
    unsigned int* __restrict__ gslices, unsigned int* __restrict__ tau20,
    float* __restrict__ cvals, int* __restrict__ cidx, int* __restrict__ ccnt,
    int V) {
  cg::grid_group grid = cg::this_grid();
  const int tid = threadIdx.x;
  const int b = blockIdx.x >> 3, c = blockIdx.x & 7;
  const int CH = V >> 3;

  __shared__ unsigned int sh[4096];   // A: lh | B: summed h | C: bv/bi
  __shared__ unsigned int ts[256];
  __shared__ unsigned int h2[256];
  __shared__ int s_bin, s_cntGT, s_found, s_c, s_base;

  float* row = logits + (size_t)b * V;

  // ---- phase A: 12-bit histogram of my chunk -> gslices[b][c][...] ----
  for (int i = tid; i < 4096; i += 256) sh[i] = 0u;
  __syncthreads();
  {
    const int base = c * CH;
    for (int i = base + tid * 4; i < base + CH; i += 1024) {
      f32x4 v = *(const f32x4*)(row + i);
      atomicAdd(&sh[f2ord(v.x) >> 20], 1u);
      atomicAdd(&sh[f2ord(v.y) >> 20], 1u);
      atomicAdd(&sh[f2ord(v.z) >> 20], 1u);
      atomicAdd(&sh[f2ord(v.w) >> 20], 1u);
    }
  }
  __syncthreads();
  {
    unsigned int* slice = gslices + ((size_t)b * 8 + c) * 4096;
    for (int i = tid; i < 4096; i += 256) slice[i] = sh[i];
  }

  grid.sync();

  // ---- phase B: per-row threshold (blocks with c==0 only) ----
  if (c == 0) {
    const unsigned int* sl = gslices + (size_t)b * 8 * 4096;
    for (int i = tid; i < 4096; i += 256) {
      unsigned int s = 0;
#pragma unroll
      for (int cc = 0; cc < 8; ++cc) s += sl[cc * 4096 + i];
      sh[i] = s;
    }
    if (tid == 0) s_found = 0;
    __syncthreads();

    int k = top_ks[b];
    if (k < 1) k = 1;
    if (k > V) k = V;
    const unsigned int uk = (unsigned int)k;

    unsigned int s0 = 0;
#pragma unroll
    for (int j = 0; j < 16; ++j) s0 += sh[16 * tid + j];
    ts[tid] = s0;
    __syncthreads();
    for (int off = 1; off < 256; off <<= 1) {
      unsigned int v = ts[tid] + ((tid + off < 256) ? ts[tid + off] : 0u);
      __syncthreads();
      ts[tid] = v;
      __syncthreads();
    }
    unsigned int above = ts[tid] - s0;
    if (above < uk && above + s0 >= uk) {
      unsigned int run = above;
      for (int j = 15; j >= 0; --j) {
        unsigned int hj = sh[16 * tid + j];
        if (run < uk && run + hj >= uk) {
          s_bin = 16 * tid + j;
          s_cntGT = (int)run;
          s_found = 1;
          break;
        }
        run += hj;
      }
    }
    __syncthreads();
    int bin = s_found ? s_bin : 0;
    int cntGT = s_found ? s_cntGT : 0;

    if (cntGT + (int)sh[bin] <= CAP) {
      if (tid == 0) { tau20[b] = ((unsigned int)bin) << 8; ccnt[b] = 0; }
    } else {
      // rare: refine by next 8 bits (this block scans the whole row)
      for (int i = tid; i < 256; i += 256) h2[i] = 0u;
      __syncthreads();
      const unsigned int binq = (unsigned int)bin;
      for (int i = tid * 4; i < V; i += 1024) {
        f32x4 v = *(const f32x4*)(row + i);
#pragma unroll
        for (int e = 0; e < 4; ++e) {
          unsigned int u = f2ord(v[e]);
          if ((u >> 20) == binq) atomicAdd(&h2[(u >> 12) & 255u], 1u);
        }
      }
      __syncthreads();
      if (tid == 0) {
        int need = k - cntGT;
        unsigned int run = 0;
        int sub = 255;
        for (; sub >= 0; --sub) {
          unsigned int hh = h2[sub];
          if (run + hh >= (unsigned int)need) break;
          run += hh;
        }
        if (sub < 0) sub = 0;
        tau20[b] = (binq << 8) | (unsigned int)sub;
        ccnt[b] = 0;
      }
    }
  }

  grid.sync();

  // ---- phase C: gather candidates (20-bit compare) + zero my chunk ----
  {
    float* bv = (float*)sh;          // [0 .. CAP)
    int* bi = (int*)(sh + CAP);      // [CAP .. 2*CAP)
    if (tid == 0) s_c = 0;
    __syncthreads();
    const unsigned int tau = tau20[b];
    const int base = c * CH;
    const f32x4 z = (f32x4){0.f, 0.f, 0.f, 0.f};
    for (int i = base + tid * 4; i < base + CH; i += 1024) {
      f32x4 v = *(const f32x4*)(row + i);
#pragma unroll
      for (int e = 0; e < 4; ++e) {
        float x = v[e];
        if ((f2ord(x) >> 12) >= tau) {
          int p = atomicAdd(&s_c, 1);
          if (p < CAP) { bv[p] = x; bi[p] = i + e; }
        }
      }
      *(f32x4*)(row + i) = z;
    }
    __syncthreads();
    int cnt = s_c;
    if (cnt > CAP) cnt = CAP;
    if (tid == 0) s_base = atomicAdd(ccnt + b, cnt);
    __syncthreads();
    const int gb = s_base;
    for (int i = tid; i < cnt; i += 256) {
      int p = gb + i;
      if (p < CAP) {
        cvals[(size_t)b * CAP + p] = bv[i];
        cidx[(size_t)b * CAP + p] = bi[i];
      }
    }
  }
}

// ---------- K3: sort, top-k/top-p (parallel scan), scatter, gumbel ----------
__global__ __launch_bounds__(1024) void finalize_k(
    const float* __restrict__ cvals, const int* __restrict__ cidx,
    const int* __restrict__ ccnt, const int* __restrict__ top_ks,
    const float* __restrict__ temps, const float* __restrict__ top_ps,
    float* __restrict__ out, int probs_base, int V, unsigned int half_n) {
  const int b = blockIdx.x, tid = threadIdx.x;
  __shared__ float vals[CAP];
  __shared__ int idxs[CAP];
  __shared__ float ex[1024];
  __shared__ float pr[1024];
  __shared__ float rsc[1024];
  __shared__ int rid[1024];
  __shared__ float s_S, s_S2;
  __shared__ int s_m;

  int cnt = ccnt[b];
  if (cnt > CAP) cnt = CAP;
  int k = top_ks[b];
  if (k < 1) k = 1;
  if (k > V) k = V;
  int K = (k < cnt) ? k : cnt;
  if (K > 1024) K = 1024;

  for (int i = tid; i < CAP; i += 1024) {
    if (i < cnt) { vals[i] = cvals[(size_t)b * CAP + i]; idxs[i] = cidx[(size_t)b * CAP + i]; }
    else         { vals[i] = -INFINITY;                  idxs[i] = 0x7fffffff; }
  }
  __syncthreads();

  for (int size = 2; size <= CAP; size <<= 1) {
    for (int stride = size >> 1; stride > 0; stride >>= 1) {
      for (int i = tid; i < CAP; i += 1024) {
        int j = i ^ stride;
        if (j > i) {
          float vi = vals[i], vj = vals[j];
          int ii = idxs[i], ij = idxs[j];
          bool iBeforeJ = (vi > vj) || (vi == vj && ii < ij);
          bool up = ((i & size) == 0);
          if (up ? !iBeforeJ : iBeforeJ) {
            vals[i] = vj; idxs[i] = ij; vals[j] = vi; idxs[j] = ii;
          }
        }
      }
      __syncthreads();
    }
  }

  const float t = temps[b];
  const float tt = (t < 1e-5f) ? 1.0f : t;
  const float l0 = vals[0] / tt;
  ex[tid] = (tid < K) ? expf(vals[tid] / tt - l0) : 0.f;
  __syncthreads();

  rsc[tid] = ex[tid];
  __syncthreads();
  for (int s = 512; s > 0; s >>= 1) {
    if (tid < s) rsc[tid] += rsc[tid + s];
    __syncthreads();
  }
  if (tid == 0) s_S = rsc[0];
  __syncthreads();
  const float S = s_S;

  const float p = top_ps[b];
  int m;
  if (p >= 1.0f - 1e-5f) {
    m = K;
  } else {
    pr[tid] = ex[tid] / S;
    __syncthreads();
    for (int off = 1; off < 1024; off <<= 1) {
      float v = pr[tid] + ((tid >= off) ? pr[tid - off] : 0.f);
      __syncthreads();
      pr[tid] = v;
      __syncthreads();
    }
    rid[tid] = (tid < K && pr[tid] <= p) ? 1 : 0;
    __syncthreads();
    for (int s = 512; s > 0; s >>= 1) {
      if (tid < s) rid[tid] += rid[tid + s];
      __syncthreads();
    }
    if (tid == 0) s_m = (rid[0] < 1) ? 1 : rid[0];
    __syncthreads();
    m = s_m;
  }
  __syncthreads();

  rsc[tid] = (tid < m) ? ex[tid] : 0.f;
  __syncthreads();
  for (int s = 512; s > 0; s >>= 1) {
    if (tid < s) rsc[tid] += rsc[tid + s];
    __syncthreads();
  }
  if (tid == 0) s_S2 = rsc[0];
  __syncthreads();
  const float S2 = s_S2;

  for (int i = tid; i < m; i += 1024)
    out[(size_t)probs_base + (size_t)b * V + idxs[i]] = ex[i] / S2;

  float best = -INFINITY;
  int bestV = 0x7fffffff;
  for (int i = tid; i < m; i += 1024) {
    int vv = idxs[i];
    unsigned int flat = (unsigned int)b * (unsigned int)V + (unsigned int)vv;
    float g = gumbel_at(flat, half_n);
    float sc = vals[i] / tt + g;
    if (sc > best || (sc == best && vv < bestV)) { best = sc; bestV = vv; }
  }
  rsc[tid] = best; rid[tid] = bestV;
  __syncthreads();
  for (int s = 512; s > 0; s >>= 1) {
    if (tid < s) {
      float o = rsc[tid + s]; int oi = rid[tid + s];
      if (o > rsc[tid] || (o == rsc[tid] && oi < rid[tid])) { rsc[tid] = o; rid[tid] = oi; }
    }
    __syncthreads();
  }
  if (tid == 0) {
    int token = (t < 1e-5f) ? idxs[0] : rid[0];
    if (token < 0 || token >= V) token = 0;
    out[b] = (float)token;
  }
}

// ---------- launch ----------
extern "C" void kernel_launch(void* const* d_in, const int* in_sizes, int n_in,
                              void* d_out, int out_size, void* d_ws, size_t ws_size,
                              hipStream_t stream) {
  const float* hidden = (const float*)d_in[0];
  const float* emb    = (const float*)d_in[1];
  const int*   lti    = (const int*)d_in[2];
  const float* temps  = (const float*)d_in[3];
  const float* tops   = (const float*)d_in[4];
  const int*   topks  = (const int*)d_in[5];

  const int B = in_sizes[2];
  const int V = (int)(((long long)out_size - B) / B);
  const int D = in_sizes[1] / V;
  const int probs_base = out_size - B * V;  // = B
  const unsigned int half_n = (unsigned int)(((long long)B * V) / 2);

  float* out = (float*)d_out;

  char* ws = (char*)d_ws;
  size_t off = 0;
  unsigned short* Ah = (unsigned short*)(ws + off); off += (size_t)B * D * sizeof(unsigned short);
  unsigned short* Al = (unsigned short*)(ws + off); off += (size_t)B * D * sizeof(unsigned short);
  float* cvals = (float*)(ws + off); off += (size_t)B * CAP * sizeof(float);
  int* cidx = (int*)(ws + off);      off += (size_t)B * CAP * sizeof(int);
  int* ccnt = (int*)(ws + off);      off += (size_t)B * sizeof(int);
  unsigned int* gslices = (unsigned int*)(ws + off); off += (size_t)B * 8 * 4096 * sizeof(unsigned int);
  unsigned int* tau20 = (unsigned int*)(ws + off);   off += (size_t)B * sizeof(unsigned int);
  (void)ws_size; (void)n_in;

  float* logits = out + probs_base;

  hipLaunchKernelGGL(gather_split, dim3(B), dim3(256), 0, stream, hidden, lti, Ah, Al, D);
  hipLaunchKernelGGL(gemm_mfma, dim3(V / BN), dim3(256), 0, stream, Ah, Al, emb, logits, D, V);
  {
    int Vv = V;
    void* args[] = {(void*)&logits, (void*)&topks, (void*)&gslices, (void*)&tau20,
                    (void*)&cvals, (void*)&cidx, (void*)&ccnt, (void*)&Vv};
    hipLaunchCooperativeKernel((const void*)select_coop, dim3(8 * B), dim3(256),
                               args, 0, stream);
  }
  hipLaunchKernelGGL(finalize_k, dim3(B), dim3(1024), 0, stream, cvals, cidx, ccnt,
                     topks, temps, tops, out, probs_base, V, half_n);
}

// Round 15
// 329.105 us; speedup vs baseline: 1.3741x; 1.3741x over previous
//
#include <hip/hip_runtime.h>
#include <hip/hip_bf16.h>
#include <math.h>

#define CAP 2048
#define PRNG_PARTITIONABLE 1

typedef __attribute__((ext_vector_type(8))) short bf16x8;
typedef __attribute__((ext_vector_type(4))) float f32x4;
typedef __attribute__((ext_vector_type(4))) unsigned int u32x4;

union B8U4 { u32x4 u; bf16x8 b; };

// LDS-only barrier (R13): drain LDS ops, NOT vmcnt.
#define BARRIER_LDS { asm volatile("s_waitcnt lgkmcnt(0)" ::: "memory"); \
                      __builtin_amdgcn_sched_barrier(0);                  \
                      __builtin_amdgcn_s_barrier(); }

// ---------- helpers ----------
__device__ __forceinline__ unsigned int f2ord(float x) {
  unsigned int u = __float_as_uint(x);
  return (u & 0x80000000u) ? ~u : (u | 0x80000000u);
}

__device__ __forceinline__ unsigned int rotl_u32(unsigned int x, int r) {
  return (x << r) | (x >> (32 - r));
}

__device__ float gumbel_at(unsigned int flat, unsigned int half_n) {
  const unsigned int ks0 = 0u;
  const unsigned int ks1 = 42u;
  const unsigned int ks2 = 0x1BD11BDAu ^ ks0 ^ ks1;
  unsigned int x0, x1;
#if PRNG_PARTITIONABLE
  x0 = 0u;
  x1 = flat;
#else
  unsigned int cnt = (flat < half_n) ? flat : (flat - half_n);
  x0 = cnt; x1 = cnt + half_n;
#endif
  x0 += ks0; x1 += ks1;
#define TF_R(r) { x0 += x1; x1 = rotl_u32(x1, r); x1 ^= x0; }
  TF_R(13) TF_R(15) TF_R(26) TF_R(6)
  x0 += ks1; x1 += ks2 + 1u;
  TF_R(17) TF_R(29) TF_R(16) TF_R(24)
  x0 += ks2; x1 += ks0 + 2u;
  TF_R(13) TF_R(15) TF_R(26) TF_R(6)
  x0 += ks0; x1 += ks1 + 3u;
  TF_R(17) TF_R(29) TF_R(16) TF_R(24)
  x0 += ks1; x1 += ks2 + 4u;
  TF_R(13) TF_R(15) TF_R(26) TF_R(6)
  x0 += ks2; x1 += ks0 + 5u;
#undef TF_R
#if PRNG_PARTITIONABLE
  unsigned int bits = x0 ^ x1;
#else
  unsigned int bits = (flat < half_n) ? x0 : x1;
#endif
  float f = __uint_as_float(0x3f800000u | (bits >> 9)) - 1.0f;
  float u = fmaxf(1e-20f, f + 1e-20f);
  return -logf(-logf(u));
}

__device__ __forceinline__ unsigned short f32_to_bf16_rne(float x) {
  unsigned int u = __float_as_uint(x);
  unsigned int r = u + 0x7fffu + ((u >> 16) & 1u);
  return (unsigned short)(r >> 16);
}
__device__ __forceinline__ float bf16u_to_f32(unsigned short h) {
  return __uint_as_float(((unsigned int)h) << 16);
}

struct HL { unsigned int h, l; };
__device__ __forceinline__ HL cvt_pair(float a, float b) {
  float2 xf = make_float2(a, b);
  __hip_bfloat162 hh = __float22bfloat162_rn(xf);
  float2 hf = __bfloat1622float2(hh);
  __hip_bfloat162 ll = __float22bfloat162_rn(make_float2(a - hf.x, b - hf.y));
  HL r;
  __builtin_memcpy(&r.h, &hh, 4);
  __builtin_memcpy(&r.l, &ll, 4);
  return r;
}

__device__ __forceinline__ f32x4 mfma16(bf16x8 a, bf16x8 b, f32x4 c) {
  return __builtin_amdgcn_mfma_f32_16x16x32_bf16(a, b, c, 0, 0, 0);
}

// ---------- K0: gather last-token rows + split to bf16 hi/lo ----------
__global__ void gather_split(const float* __restrict__ hidden, const int* __restrict__ lti,
                             unsigned short* __restrict__ Ah, unsigned short* __restrict__ Al,
                             int D) {
  int b = blockIdx.x;
  const float* src = hidden + (size_t)lti[b] * D;
  for (int i = threadIdx.x; i < D; i += blockDim.x) {
    float x = src[i];
    unsigned short h = f32_to_bf16_rne(x);
    float r = x - bf16u_to_f32(h);
    Ah[(size_t)b * D + i] = h;
    Al[(size_t)b * D + i] = f32_to_bf16_rne(r);
  }
}

// ---------- K1: logits = A @ E^T via bf16x3 MFMA (R13, 227us) ----------
#define BN 128
#define BK 64
__global__ __launch_bounds__(256) void gemm_mfma(
    const unsigned short* __restrict__ Ahg, const unsigned short* __restrict__ Alg,
    const float* __restrict__ E, float* __restrict__ outL, int D, int V) {
  __shared__ __align__(16) float BS[128 * 64];
  __shared__ __align__(16) unsigned short AhS[64 * 64];
  __shared__ __align__(16) unsigned short AlS[64 * 64];

  const int t = threadIdx.x;
  const int lane = t & 63;
  const int wv = t >> 6;
  const long n0 = (long)blockIdx.x * BN;
  const int am = t >> 2, ao = t & 3;

  f32x4 acc[4][2];
#pragma unroll
  for (int i = 0; i < 4; ++i)
#pragma unroll
    for (int j = 0; j < 2; ++j) acc[i][j] = (f32x4){0.f, 0.f, 0.f, 0.f};

  f32x4 bA[8], bB[8];
  bf16x8 aA[4], aB[4];

  auto LOAD = [&](f32x4* br, bf16x8* ar, int k0) {
#pragma unroll
    for (int q = 0; q < 4; ++q) {
      int gi = q * 256 + t, n = gi >> 3, o = gi & 7;
      const float* s = E + (size_t)(n0 + n) * D + k0 + o * 8;
      br[2 * q] = *(const f32x4*)s;
      br[2 * q + 1] = *(const f32x4*)(s + 4);
    }
    const unsigned short* ph = Ahg + (size_t)am * D + k0 + ao * 16;
    ar[0] = *(const bf16x8*)ph;
    ar[1] = *(const bf16x8*)(ph + 8);
    const unsigned short* pl = Alg + (size_t)am * D + k0 + ao * 16;
    ar[2] = *(const bf16x8*)pl;
    ar[3] = *(const bf16x8*)(pl + 8);
  };

  auto STAGE = [&](f32x4* br, bf16x8* ar) {
#pragma unroll
    for (int q = 0; q < 4; ++q) {
      int gi = q * 256 + t, n = gi >> 3, o = gi & 7;
      int pg0 = (2 * o) ^ (n & 7);
      int pg1 = (2 * o + 1) ^ (n & 7);
      *(f32x4*)&BS[n * 64 + pg0 * 4] = br[2 * q];
      *(f32x4*)&BS[n * 64 + pg1 * 4] = br[2 * q + 1];
    }
    int g0 = ao * 2;
    int off0 = am * 64 + ((g0 ^ (am & 7)) * 8);
    int off1 = am * 64 + (((g0 + 1) ^ (am & 7)) * 8);
    *(bf16x8*)&AhS[off0] = ar[0];
    *(bf16x8*)&AhS[off1] = ar[1];
    *(bf16x8*)&AlS[off0] = ar[2];
    *(bf16x8*)&AlS[off1] = ar[3];
  };

  auto COMPUTE = [&]() {
#pragma unroll
    for (int k32 = 0; k32 < 2; ++k32) {
      const int og = k32 * 4 + (lane >> 4);
      bf16x8 ah[4], al[4], bh[2], bl[2];
#pragma unroll
      for (int mf = 0; mf < 4; ++mf) {
        int r = mf * 16 + (lane & 15);
        int off = r * 64 + ((og ^ (r & 7)) * 8);
        ah[mf] = *(const bf16x8*)&AhS[off];
        al[mf] = *(const bf16x8*)&AlS[off];
      }
#pragma unroll
      for (int nf = 0; nf < 2; ++nf) {
        int n = wv * 32 + nf * 16 + (lane & 15);
        int pg0 = (2 * og) ^ (n & 7);
        int pg1 = (2 * og + 1) ^ (n & 7);
        f32x4 v0 = *(const f32x4*)&BS[n * 64 + pg0 * 4];
        f32x4 v1 = *(const f32x4*)&BS[n * 64 + pg1 * 4];
        HL p0 = cvt_pair(v0.x, v0.y);
        HL p1 = cvt_pair(v0.z, v0.w);
        HL p2 = cvt_pair(v1.x, v1.y);
        HL p3 = cvt_pair(v1.z, v1.w);
        B8U4 hb, lb;
        hb.u = (u32x4){p0.h, p1.h, p2.h, p3.h};
        lb.u = (u32x4){p0.l, p1.l, p2.l, p3.l};
        bh[nf] = hb.b;
        bl[nf] = lb.b;
      }
      __builtin_amdgcn_s_setprio(1);
#pragma unroll
      for (int mf = 0; mf < 4; ++mf)
#pragma unroll
        for (int nf = 0; nf < 2; ++nf) {
          acc[mf][nf] = mfma16(ah[mf], bh[nf], acc[mf][nf]);
          acc[mf][nf] = mfma16(ah[mf], bl[nf], acc[mf][nf]);
          acc[mf][nf] = mfma16(al[mf], bh[nf], acc[mf][nf]);
        }
      __builtin_amdgcn_s_setprio(0);
    }
  };

  LOAD(bA, aA, 0);
#pragma unroll 1
  for (int k0 = 0; k0 < D; k0 += 2 * BK) {
    if (k0 + BK < D) LOAD(bB, aB, k0 + BK);
    BARRIER_LDS;
    STAGE(bA, aA);
    BARRIER_LDS;
    COMPUTE();
    if (k0 + 2 * BK < D) LOAD(bA, aA, k0 + 2 * BK);
    BARRIER_LDS;
    STAGE(bB, aB);
    BARRIER_LDS;
    COMPUTE();
  }

#pragma unroll
  for (int mf = 0; mf < 4; ++mf)
#pragma unroll
    for (int nf = 0; nf < 2; ++nf) {
      long v = n0 + wv * 32 + nf * 16 + (lane & 15);
      int rbase = mf * 16 + ((lane >> 4) << 2);
#pragma unroll
      for (int reg = 0; reg < 4; ++reg)
        outL[(size_t)(rbase + reg) * V + v] = acc[mf][nf][reg];
    }
}

// ---------- K2a: per-chunk 12-bit hist -> slice (no global atomics);
//             c==0 block also zeroes ccnt[b] ----------
__global__ __launch_bounds__(256) void hist_k(
    const float* __restrict__ logits, unsigned int* __restrict__ gslices,
    int* __restrict__ ccnt, int V) {
  const int b = blockIdx.x >> 3, c = blockIdx.x & 7;
  const int CH = V >> 3;
  const float* row = logits + (size_t)b * V;
  __shared__ unsigned int lh[4096];
  const int tid = threadIdx.x;
  for (int i = tid; i < 4096; i += 256) lh[i] = 0u;
  if (c == 0 && tid == 0) ccnt[b] = 0;
  __syncthreads();
  const int base = c * CH;
  for (int i = base + tid * 4; i < base + CH; i += 1024) {
    f32x4 v = *(const f32x4*)(row + i);
    atomicAdd(&lh[f2ord(v.x) >> 20], 1u);
    atomicAdd(&lh[f2ord(v.y) >> 20], 1u);
    atomicAdd(&lh[f2ord(v.z) >> 20], 1u);
    atomicAdd(&lh[f2ord(v.w) >> 20], 1u);
  }
  __syncthreads();
  unsigned int* slice = gslices + ((size_t)b * 8 + c) * 4096;
  for (int i = tid; i < 4096; i += 256) slice[i] = lh[i];
}

// ---------- K2b: gather — inline threshold (sum slices + scan) + gather +
//             zero chunk (8 blocks/row) ----------
__global__ __launch_bounds__(256) void gather_k(
    float* __restrict__ logits, const unsigned int* __restrict__ gslices,
    const int* __restrict__ top_ks,
    float* __restrict__ cvals, int* __restrict__ cidx, int* __restrict__ ccnt,
    int V) {
  const int b = blockIdx.x >> 3, c = blockIdx.x & 7;
  const int CH = V >> 3;
  float* row = logits + (size_t)b * V;
  __shared__ unsigned int sh[4096];   // summed hist, then reused as bv/bi
  __shared__ unsigned int ts[256];
  __shared__ unsigned int h2[256];
  __shared__ int s_bin, s_cntGT, s_found, s_c, s_base;
  const int tid = threadIdx.x;

  // ---- inline threshold: sum 8 slices, 256-thread suffix scan ----
  {
    const unsigned int* sl = gslices + (size_t)b * 8 * 4096;
    for (int i = tid; i < 4096; i += 256) {
      unsigned int s = 0;
#pragma unroll
      for (int cc = 0; cc < 8; ++cc) s += sl[cc * 4096 + i];
      sh[i] = s;
    }
    if (tid == 0) s_found = 0;
    __syncthreads();

    int k = top_ks[b];
    if (k < 1) k = 1;
    if (k > V) k = V;
    const unsigned int uk = (unsigned int)k;

    unsigned int s0 = 0;
#pragma unroll
    for (int j = 0; j < 16; ++j) s0 += sh[16 * tid + j];
    ts[tid] = s0;
    __syncthreads();
    for (int off = 1; off < 256; off <<= 1) {
      unsigned int v = ts[tid] + ((tid + off < 256) ? ts[tid + off] : 0u);
      __syncthreads();
      ts[tid] = v;
      __syncthreads();
    }
    unsigned int above = ts[tid] - s0;
    if (above < uk && above + s0 >= uk) {
      unsigned int run = above;
      for (int j = 15; j >= 0; --j) {
        unsigned int hj = sh[16 * tid + j];
        if (run < uk && run + hj >= uk) {
          s_bin = 16 * tid + j;
          s_cntGT = (int)run;
          s_found = 1;
          break;
        }
        run += hj;
      }
    }
    __syncthreads();
    int bin = s_found ? s_bin : 0;
    int cntGT = s_found ? s_cntGT : 0;
    unsigned int tau;
    if (cntGT + (int)sh[bin] <= CAP) {
      tau = ((unsigned int)bin) << 8;
    } else {
      // rare: refine by next 8 bits — redundant full-row scan per block
      for (int i = tid; i < 256; i += 256) h2[i] = 0u;
      __syncthreads();
      const unsigned int binq = (unsigned int)bin;
      for (int i = tid * 4; i < V; i += 1024) {
        f32x4 v = *(const f32x4*)(row + i);
#pragma unroll
        for (int e = 0; e < 4; ++e) {
          unsigned int u = f2ord(v[e]);
          if ((u >> 20) == binq) atomicAdd(&h2[(u >> 12) & 255u], 1u);
        }
      }
      __syncthreads();
      int need = k - cntGT;
      unsigned int run = 0;
      int sub = 255;
      for (; sub >= 0; --sub) {
        unsigned int hh = h2[sub];
        if (run + hh >= (unsigned int)need) break;
        run += hh;
      }
      if (sub < 0) sub = 0;
      tau = (((unsigned int)bin) << 8) | (unsigned int)sub;
    }
    __syncthreads();  // done reading sh as hist
    ts[0] = tau;      // stash tau (any slot safe post-sync)
    __syncthreads();
  }
  const unsigned int tau = ts[0];

  // ---- gather + zero chunk (sh reused as bv/bi) ----
  float* bv = (float*)sh;
  int* bi = (int*)(sh + CAP);
  if (tid == 0) s_c = 0;
  __syncthreads();
  const int base = c * CH;
  const f32x4 z = (f32x4){0.f, 0.f, 0.f, 0.f};
  for (int i = base + tid * 4; i < base + CH; i += 1024) {
    f32x4 v = *(const f32x4*)(row + i);
#pragma unroll
    for (int e = 0; e < 4; ++e) {
      float x = v[e];
      if ((f2ord(x) >> 12) >= tau) {
        int p = atomicAdd(&s_c, 1);
        if (p < CAP) { bv[p] = x; bi[p] = i + e; }
      }
    }
    *(f32x4*)(row + i) = z;
  }
  __syncthreads();
  int cnt = s_c;
  if (cnt > CAP) cnt = CAP;
  if (tid == 0) s_base = atomicAdd(ccnt + b, cnt);
  __syncthreads();
  const int gb = s_base;
  for (int i = tid; i < cnt; i += 256) {
    int p = gb + i;
    if (p < CAP) {
      cvals[(size_t)b * CAP + p] = bv[i];
      cidx[(size_t)b * CAP + p] = bi[i];
    }
  }
}

// ---------- K3: sort, top-k/top-p (parallel scan), scatter, gumbel ----------
__global__ __launch_bounds__(1024) void finalize_k(
    const float* __restrict__ cvals, const int* __restrict__ cidx,
    const int* __restrict__ ccnt, const int* __restrict__ top_ks,
    const float* __restrict__ temps, const float* __restrict__ top_ps,
    float* __restrict__ out, int probs_base, int V, unsigned int half_n) {
  const int b = blockIdx.x, tid = threadIdx.x;
  __shared__ float vals[CAP];
  __shared__ int idxs[CAP];
  __shared__ float ex[1024];
  __shared__ float pr[1024];
  __shared__ float rsc[1024];
  __shared__ int rid[1024];
  __shared__ float s_S, s_S2;
  __shared__ int s_m;

  int cnt = ccnt[b];
  if (cnt > CAP) cnt = CAP;
  int k = top_ks[b];
  if (k < 1) k = 1;
  if (k > V) k = V;
  int K = (k < cnt) ? k : cnt;
  if (K > 1024) K = 1024;

  for (int i = tid; i < CAP; i += 1024) {
    if (i < cnt) { vals[i] = cvals[(size_t)b * CAP + i]; idxs[i] = cidx[(size_t)b * CAP + i]; }
    else         { vals[i] = -INFINITY;                  idxs[i] = 0x7fffffff; }
  }
  __syncthreads();

  for (int size = 2; size <= CAP; size <<= 1) {
    for (int stride = size >> 1; stride > 0; stride >>= 1) {
      for (int i = tid; i < CAP; i += 1024) {
        int j = i ^ stride;
        if (j > i) {
          float vi = vals[i], vj = vals[j];
          int ii = idxs[i], ij = idxs[j];
          bool iBeforeJ = (vi > vj) || (vi == vj && ii < ij);
          bool up = ((i & size) == 0);
          if (up ? !iBeforeJ : iBeforeJ) {
            vals[i] = vj; idxs[i] = ij; vals[j] = vi; idxs[j] = ii;
          }
        }
      }
      __syncthreads();
    }
  }

  const float t = temps[b];
  const float tt = (t < 1e-5f) ? 1.0f : t;
  const float l0 = vals[0] / tt;
  ex[tid] = (tid < K) ? expf(vals[tid] / tt - l0) : 0.f;
  __syncthreads();

  rsc[tid] = ex[tid];
  __syncthreads();
  for (int s = 512; s > 0; s >>= 1) {
    if (tid < s) rsc[tid] += rsc[tid + s];
    __syncthreads();
  }
  if (tid == 0) s_S = rsc[0];
  __syncthreads();
  const float S = s_S;

  const float p = top_ps[b];
  int m;
  if (p >= 1.0f - 1e-5f) {
    m = K;
  } else {
    pr[tid] = ex[tid] / S;
    __syncthreads();
    for (int off = 1; off < 1024; off <<= 1) {
      float v = pr[tid] + ((tid >= off) ? pr[tid - off] : 0.f);
      __syncthreads();
      pr[tid] = v;
      __syncthreads();
    }
    rid[tid] = (tid < K && pr[tid] <= p) ? 1 : 0;
    __syncthreads();
    for (int s = 512; s > 0; s >>= 1) {
      if (tid < s) rid[tid] += rid[tid + s];
      __syncthreads();
    }
    if (tid == 0) s_m = (rid[0] < 1) ? 1 : rid[0];
    __syncthreads();
    m = s_m;
  }
  __syncthreads();

  rsc[tid] = (tid < m) ? ex[tid] : 0.f;
  __syncthreads();
  for (int s = 512; s > 0; s >>= 1) {
    if (tid < s) rsc[tid] += rsc[tid + s];
    __syncthreads();
  }
  if (tid == 0) s_S2 = rsc[0];
  __syncthreads();
  const float S2 = s_S2;

  for (int i = tid; i < m; i += 1024)
    out[(size_t)probs_base + (size_t)b * V + idxs[i]] = ex[i] / S2;

  float best = -INFINITY;
  int bestV = 0x7fffffff;
  for (int i = tid; i < m; i += 1024) {
    int vv = idxs[i];
    unsigned int flat = (unsigned int)b * (unsigned int)V + (unsigned int)vv;
    float g = gumbel_at(flat, half_n);
    float sc = vals[i] / tt + g;
    if (sc > best || (sc == best && vv < bestV)) { best = sc; bestV = vv; }
  }
  rsc[tid] = best; rid[tid] = bestV;
  __syncthreads();
  for (int s = 512; s > 0; s >>= 1) {
    if (tid < s) {
      float o = rsc[tid + s]; int oi = rid[tid + s];
      if (o > rsc[tid] || (o == rsc[tid] && oi < rid[tid])) { rsc[tid] = o; rid[tid] = oi; }
    }
    __syncthreads();
  }
  if (tid == 0) {
    int token = (t < 1e-5f) ? idxs[0] : rid[0];
    if (token < 0 || token >= V) token = 0;
    out[b] = (float)token;
  }
}

// ---------- launch ----------
extern "C" void kernel_launch(void* const* d_in, const int* in_sizes, int n_in,
                              void* d_out, int out_size, void* d_ws, size_t ws_size,
                              hipStream_t stream) {
  const float* hidden = (const float*)d_in[0];
  const float* emb    = (const float*)d_in[1];
  const int*   lti    = (const int*)d_in[2];
  const float* temps  = (const float*)d_in[3];
  const float* tops   = (const float*)d_in[4];
  const int*   topks  = (const int*)d_in[5];

  const int B = in_sizes[2];
  const int V = (int)(((long long)out_size - B) / B);
  const int D = in_sizes[1] / V;
  const int probs_base = out_size - B * V;  // = B
  const unsigned int half_n = (unsigned int)(((long long)B * V) / 2);

  float* out = (float*)d_out;

  char* ws = (char*)d_ws;
  size_t off = 0;
  unsigned short* Ah = (unsigned short*)(ws + off); off += (size_t)B * D * sizeof(unsigned short);
  unsigned short* Al = (unsigned short*)(ws + off); off += (size_t)B * D * sizeof(unsigned short);
  float* cvals = (float*)(ws + off); off += (size_t)B * CAP * sizeof(float);
  int* cidx = (int*)(ws + off);      off += (size_t)B * CAP * sizeof(int);
  int* ccnt = (int*)(ws + off);      off += (size_t)B * sizeof(int);
  unsigned int* gslices = (unsigned int*)(ws + off); off += (size_t)B * 8 * 4096 * sizeof(unsigned int);
  (void)ws_size; (void)n_in;

  float* logits = out + probs_base;

  hipLaunchKernelGGL(gather_split, dim3(B), dim3(256), 0, stream, hidden, lti, Ah, Al, D);
  hipLaunchKernelGGL(gemm_mfma, dim3(V / BN), dim3(256), 0, stream, Ah, Al, emb, logits, D, V);
  hipLaunchKernelGGL(hist_k, dim3(8 * B), dim3(256), 0, stream, logits, gslices, ccnt, V);
  hipLaunchKernelGGL(gather_k, dim3(8 * B), dim3(256), 0, stream, logits, gslices, topks,
                     cvals, cidx, ccnt, V);
  hipLaunchKernelGGL(finalize_k, dim3(B), dim3(1024), 0, stream, cvals, cidx, ccnt,
                     topks, temps, tops, out, probs_base, V, half_n);
}

// Round 16
// 327.217 us; speedup vs baseline: 1.3820x; 1.0058x over previous
//
#include <hip/hip_runtime.h>
#include <hip/hip_bf16.h>
#include <math.h>

#define CAP 2048
#define PRNG_PARTITIONABLE 1

typedef __attribute__((ext_vector_type(8))) short bf16x8;
typedef __attribute__((ext_vector_type(4))) float f32x4;
typedef __attribute__((ext_vector_type(4))) unsigned int u32x4;

union B8U4 { u32x4 u; bf16x8 b; };

// LDS-only barrier (R13): drain LDS ops, NOT vmcnt.
#define BARRIER_LDS { asm volatile("s_waitcnt lgkmcnt(0)" ::: "memory"); \
                      __builtin_amdgcn_sched_barrier(0);                  \
                      __builtin_amdgcn_s_barrier(); }

// ---------- helpers ----------
__device__ __forceinline__ unsigned int f2ord(float x) {
  unsigned int u = __float_as_uint(x);
  return (u & 0x80000000u) ? ~u : (u | 0x80000000u);
}

__device__ __forceinline__ unsigned int rotl_u32(unsigned int x, int r) {
  return (x << r) | (x >> (32 - r));
}

__device__ float gumbel_at(unsigned int flat, unsigned int half_n) {
  const unsigned int ks0 = 0u;
  const unsigned int ks1 = 42u;
  const unsigned int ks2 = 0x1BD11BDAu ^ ks0 ^ ks1;
  unsigned int x0, x1;
#if PRNG_PARTITIONABLE
  x0 = 0u;
  x1 = flat;
#else
  unsigned int cnt = (flat < half_n) ? flat : (flat - half_n);
  x0 = cnt; x1 = cnt + half_n;
#endif
  x0 += ks0; x1 += ks1;
#define TF_R(r) { x0 += x1; x1 = rotl_u32(x1, r); x1 ^= x0; }
  TF_R(13) TF_R(15) TF_R(26) TF_R(6)
  x0 += ks1; x1 += ks2 + 1u;
  TF_R(17) TF_R(29) TF_R(16) TF_R(24)
  x0 += ks2; x1 += ks0 + 2u;
  TF_R(13) TF_R(15) TF_R(26) TF_R(6)
  x0 += ks0; x1 += ks1 + 3u;
  TF_R(17) TF_R(29) TF_R(16) TF_R(24)
  x0 += ks1; x1 += ks2 + 4u;
  TF_R(13) TF_R(15) TF_R(26) TF_R(6)
  x0 += ks2; x1 += ks0 + 5u;
#undef TF_R
#if PRNG_PARTITIONABLE
  unsigned int bits = x0 ^ x1;
#else
  unsigned int bits = (flat < half_n) ? x0 : x1;
#endif
  float f = __uint_as_float(0x3f800000u | (bits >> 9)) - 1.0f;
  float u = fmaxf(1e-20f, f + 1e-20f);
  return -logf(-logf(u));
}

__device__ __forceinline__ unsigned short f32_to_bf16_rne(float x) {
  unsigned int u = __float_as_uint(x);
  unsigned int r = u + 0x7fffu + ((u >> 16) & 1u);
  return (unsigned short)(r >> 16);
}
__device__ __forceinline__ float bf16u_to_f32(unsigned short h) {
  return __uint_as_float(((unsigned int)h) << 16);
}

struct HL { unsigned int h, l; };
__device__ __forceinline__ HL cvt_pair(float a, float b) {
  float2 xf = make_float2(a, b);
  __hip_bfloat162 hh = __float22bfloat162_rn(xf);
  float2 hf = __bfloat1622float2(hh);
  __hip_bfloat162 ll = __float22bfloat162_rn(make_float2(a - hf.x, b - hf.y));
  HL r;
  __builtin_memcpy(&r.h, &hh, 4);
  __builtin_memcpy(&r.l, &ll, 4);
  return r;
}

__device__ __forceinline__ f32x4 mfma16(bf16x8 a, bf16x8 b, f32x4 c) {
  return __builtin_amdgcn_mfma_f32_16x16x32_bf16(a, b, c, 0, 0, 0);
}

// ---------- K0: gather last-token rows + split to bf16 hi/lo ----------
__global__ void gather_split(const float* __restrict__ hidden, const int* __restrict__ lti,
                             unsigned short* __restrict__ Ah, unsigned short* __restrict__ Al,
                             int D) {
  int b = blockIdx.x;
  const float* src = hidden + (size_t)lti[b] * D;
  for (int i = threadIdx.x; i < D; i += blockDim.x) {
    float x = src[i];
    unsigned short h = f32_to_bf16_rne(x);
    float r = x - bf16u_to_f32(h);
    Ah[(size_t)b * D + i] = h;
    Al[(size_t)b * D + i] = f32_to_bf16_rne(r);
  }
}

// ---------- K1: logits = A @ E^T via bf16x3 MFMA (R13, 227us) ----------
#define BN 128
#define BK 64
__global__ __launch_bounds__(256) void gemm_mfma(
    const unsigned short* __restrict__ Ahg, const unsigned short* __restrict__ Alg,
    const float* __restrict__ E, float* __restrict__ outL, int D, int V) {
  __shared__ __align__(16) float BS[128 * 64];
  __shared__ __align__(16) unsigned short AhS[64 * 64];
  __shared__ __align__(16) unsigned short AlS[64 * 64];

  const int t = threadIdx.x;
  const int lane = t & 63;
  const int wv = t >> 6;
  const long n0 = (long)blockIdx.x * BN;
  const int am = t >> 2, ao = t & 3;

  f32x4 acc[4][2];
#pragma unroll
  for (int i = 0; i < 4; ++i)
#pragma unroll
    for (int j = 0; j < 2; ++j) acc[i][j] = (f32x4){0.f, 0.f, 0.f, 0.f};

  f32x4 bA[8], bB[8];
  bf16x8 aA[4], aB[4];

  auto LOAD = [&](f32x4* br, bf16x8* ar, int k0) {
#pragma unroll
    for (int q = 0; q < 4; ++q) {
      int gi = q * 256 + t, n = gi >> 3, o = gi & 7;
      const float* s = E + (size_t)(n0 + n) * D + k0 + o * 8;
      br[2 * q] = *(const f32x4*)s;
      br[2 * q + 1] = *(const f32x4*)(s + 4);
    }
    const unsigned short* ph = Ahg + (size_t)am * D + k0 + ao * 16;
    ar[0] = *(const bf16x8*)ph;
    ar[1] = *(const bf16x8*)(ph + 8);
    const unsigned short* pl = Alg + (size_t)am * D + k0 + ao * 16;
    ar[2] = *(const bf16x8*)pl;
    ar[3] = *(const bf16x8*)(pl + 8);
  };

  auto STAGE = [&](f32x4* br, bf16x8* ar) {
#pragma unroll
    for (int q = 0; q < 4; ++q) {
      int gi = q * 256 + t, n = gi >> 3, o = gi & 7;
      int pg0 = (2 * o) ^ (n & 7);
      int pg1 = (2 * o + 1) ^ (n & 7);
      *(f32x4*)&BS[n * 64 + pg0 * 4] = br[2 * q];
      *(f32x4*)&BS[n * 64 + pg1 * 4] = br[2 * q + 1];
    }
    int g0 = ao * 2;
    int off0 = am * 64 + ((g0 ^ (am & 7)) * 8);
    int off1 = am * 64 + (((g0 + 1) ^ (am & 7)) * 8);
    *(bf16x8*)&AhS[off0] = ar[0];
    *(bf16x8*)&AhS[off1] = ar[1];
    *(bf16x8*)&AlS[off0] = ar[2];
    *(bf16x8*)&AlS[off1] = ar[3];
  };

  auto COMPUTE = [&]() {
#pragma unroll
    for (int k32 = 0; k32 < 2; ++k32) {
      const int og = k32 * 4 + (lane >> 4);
      bf16x8 ah[4], al[4], bh[2], bl[2];
#pragma unroll
      for (int mf = 0; mf < 4; ++mf) {
        int r = mf * 16 + (lane & 15);
        int off = r * 64 + ((og ^ (r & 7)) * 8);
        ah[mf] = *(const bf16x8*)&AhS[off];
        al[mf] = *(const bf16x8*)&AlS[off];
      }
#pragma unroll
      for (int nf = 0; nf < 2; ++nf) {
        int n = wv * 32 + nf * 16 + (lane & 15);
        int pg0 = (2 * og) ^ (n & 7);
        int pg1 = (2 * og + 1) ^ (n & 7);
        f32x4 v0 = *(const f32x4*)&BS[n * 64 + pg0 * 4];
        f32x4 v1 = *(const f32x4*)&BS[n * 64 + pg1 * 4];
        HL p0 = cvt_pair(v0.x, v0.y);
        HL p1 = cvt_pair(v0.z, v0.w);
        HL p2 = cvt_pair(v1.x, v1.y);
        HL p3 = cvt_pair(v1.z, v1.w);
        B8U4 hb, lb;
        hb.u = (u32x4){p0.h, p1.h, p2.h, p3.h};
        lb.u = (u32x4){p0.l, p1.l, p2.l, p3.l};
        bh[nf] = hb.b;
        bl[nf] = lb.b;
      }
      __builtin_amdgcn_s_setprio(1);
#pragma unroll
      for (int mf = 0; mf < 4; ++mf)
#pragma unroll
        for (int nf = 0; nf < 2; ++nf) {
          acc[mf][nf] = mfma16(ah[mf], bh[nf], acc[mf][nf]);
          acc[mf][nf] = mfma16(ah[mf], bl[nf], acc[mf][nf]);
          acc[mf][nf] = mfma16(al[mf], bh[nf], acc[mf][nf]);
        }
      __builtin_amdgcn_s_setprio(0);
    }
  };

  LOAD(bA, aA, 0);
#pragma unroll 1
  for (int k0 = 0; k0 < D; k0 += 2 * BK) {
    if (k0 + BK < D) LOAD(bB, aB, k0 + BK);
    BARRIER_LDS;
    STAGE(bA, aA);
    BARRIER_LDS;
    COMPUTE();
    if (k0 + 2 * BK < D) LOAD(bA, aA, k0 + 2 * BK);
    BARRIER_LDS;
    STAGE(bB, aB);
    BARRIER_LDS;
    COMPUTE();
  }

#pragma unroll
  for (int mf = 0; mf < 4; ++mf)
#pragma unroll
    for (int nf = 0; nf < 2; ++nf) {
      long v = n0 + wv * 32 + nf * 16 + (lane & 15);
      int rbase = mf * 16 + ((lane >> 4) << 2);
#pragma unroll
      for (int reg = 0; reg < 4; ++reg)
        outL[(size_t)(rbase + reg) * V + v] = acc[mf][nf][reg];
    }
}

// ---------- K2a: per-chunk 12-bit hist -> slice; c==0 zeroes ccnt ----------
__global__ __launch_bounds__(256) void hist_k(
    const float* __restrict__ logits, unsigned int* __restrict__ gslices,
    int* __restrict__ ccnt, int V) {
  const int b = blockIdx.x >> 3, c = blockIdx.x & 7;
  const int CH = V >> 3;
  const float* row = logits + (size_t)b * V;
  __shared__ unsigned int lh[4096];
  const int tid = threadIdx.x;
  for (int i = tid; i < 4096; i += 256) lh[i] = 0u;
  if (c == 0 && tid == 0) ccnt[b] = 0;
  __syncthreads();
  const int base = c * CH;
  for (int i = base + tid * 4; i < base + CH; i += 1024) {
    f32x4 v = *(const f32x4*)(row + i);
    atomicAdd(&lh[f2ord(v.x) >> 20], 1u);
    atomicAdd(&lh[f2ord(v.y) >> 20], 1u);
    atomicAdd(&lh[f2ord(v.z) >> 20], 1u);
    atomicAdd(&lh[f2ord(v.w) >> 20], 1u);
  }
  __syncthreads();
  unsigned int* slice = gslices + ((size_t)b * 8 + c) * 4096;
  for (int i = tid; i < 4096; i += 256) slice[i] = lh[i];
}

// ---------- K2b: gather — inline threshold + gather + zero chunk ----------
__global__ __launch_bounds__(256) void gather_k(
    float* __restrict__ logits, const unsigned int* __restrict__ gslices,
    const int* __restrict__ top_ks,
    float* __restrict__ cvals, int* __restrict__ cidx, int* __restrict__ ccnt,
    unsigned int* __restrict__ tau_out, int V) {
  const int b = blockIdx.x >> 3, c = blockIdx.x & 7;
  const int CH = V >> 3;
  float* row = logits + (size_t)b * V;
  __shared__ unsigned int sh[4096];
  __shared__ unsigned int ts[256];
  __shared__ unsigned int h2[256];
  __shared__ int s_bin, s_cntGT, s_found, s_c, s_base;
  const int tid = threadIdx.x;

  {
    const unsigned int* sl = gslices + (size_t)b * 8 * 4096;
    for (int i = tid; i < 4096; i += 256) {
      unsigned int s = 0;
#pragma unroll
      for (int cc = 0; cc < 8; ++cc) s += sl[cc * 4096 + i];
      sh[i] = s;
    }
    if (tid == 0) s_found = 0;
    __syncthreads();

    int k = top_ks[b];
    if (k < 1) k = 1;
    if (k > V) k = V;
    const unsigned int uk = (unsigned int)k;

    unsigned int s0 = 0;
#pragma unroll
    for (int j = 0; j < 16; ++j) s0 += sh[16 * tid + j];
    ts[tid] = s0;
    __syncthreads();
    for (int off = 1; off < 256; off <<= 1) {
      unsigned int v = ts[tid] + ((tid + off < 256) ? ts[tid + off] : 0u);
      __syncthreads();
      ts[tid] = v;
      __syncthreads();
    }
    unsigned int above = ts[tid] - s0;
    if (above < uk && above + s0 >= uk) {
      unsigned int run = above;
      for (int j = 15; j >= 0; --j) {
        unsigned int hj = sh[16 * tid + j];
        if (run < uk && run + hj >= uk) {
          s_bin = 16 * tid + j;
          s_cntGT = (int)run;
          s_found = 1;
          break;
        }
        run += hj;
      }
    }
    __syncthreads();
    int bin = s_found ? s_bin : 0;
    int cntGT = s_found ? s_cntGT : 0;
    unsigned int tau;
    if (cntGT + (int)sh[bin] <= CAP) {
      tau = ((unsigned int)bin) << 8;
    } else {
      for (int i = tid; i < 256; i += 256) h2[i] = 0u;
      __syncthreads();
      const unsigned int binq = (unsigned int)bin;
      for (int i = tid * 4; i < V; i += 1024) {
        f32x4 v = *(const f32x4*)(row + i);
#pragma unroll
        for (int e = 0; e < 4; ++e) {
          unsigned int u = f2ord(v[e]);
          if ((u >> 20) == binq) atomicAdd(&h2[(u >> 12) & 255u], 1u);
        }
      }
      __syncthreads();
      int need = k - cntGT;
      unsigned int run = 0;
      int sub = 255;
      for (; sub >= 0; --sub) {
        unsigned int hh = h2[sub];
        if (run + hh >= (unsigned int)need) break;
        run += hh;
      }
      if (sub < 0) sub = 0;
      tau = (((unsigned int)bin) << 8) | (unsigned int)sub;
    }
    __syncthreads();
    ts[0] = tau;
    __syncthreads();
  }
  const unsigned int tau = ts[0];
  if (tid == 0) tau_out[b] = tau;

  float* bv = (float*)sh;
  int* bi = (int*)(sh + CAP);
  if (tid == 0) s_c = 0;
  __syncthreads();
  const int base = c * CH;
  const f32x4 z = (f32x4){0.f, 0.f, 0.f, 0.f};
  for (int i = base + tid * 4; i < base + CH; i += 1024) {
    f32x4 v = *(const f32x4*)(row + i);
#pragma unroll
    for (int e = 0; e < 4; ++e) {
      float x = v[e];
      if ((f2ord(x) >> 12) >= tau) {
        int p = atomicAdd(&s_c, 1);
        if (p < CAP) { bv[p] = x; bi[p] = i + e; }
      }
    }
    *(f32x4*)(row + i) = z;
  }
  __syncthreads();
  int cnt = s_c;
  if (cnt > CAP) cnt = CAP;
  if (tid == 0) s_base = atomicAdd(ccnt + b, cnt);
  __syncthreads();
  const int gb = s_base;
  for (int i = tid; i < cnt; i += 256) {
    int p = gb + i;
    if (p < CAP) {
      cvals[(size_t)b * CAP + p] = bv[i];
      cidx[(size_t)b * CAP + p] = bi[i];
    }
  }
}

// ---------- K3: refine-select to ~k, compact, small bitonic, softmax ------
__global__ __launch_bounds__(1024) void finalize_k(
    const float* __restrict__ cvals, const int* __restrict__ cidx,
    const int* __restrict__ ccnt, const unsigned int* __restrict__ tau20,
    const int* __restrict__ top_ks,
    const float* __restrict__ temps, const float* __restrict__ top_ps,
    float* __restrict__ out, int probs_base, int V, unsigned int half_n) {
  const int b = blockIdx.x, tid = threadIdx.x;
  __shared__ float vals[CAP];
  __shared__ int idxs[CAP];
  __shared__ float sv[CAP];
  __shared__ int si[CAP];
  __shared__ float ex[1024];
  __shared__ float pr[1024];
  __shared__ float rsc[1024];
  __shared__ int rid[1024];
  __shared__ unsigned int h2[256];
  __shared__ int s_kc, s_sub;
  __shared__ float s_S, s_S2;
  __shared__ int s_m;

  int cnt = ccnt[b];
  if (cnt > CAP) cnt = CAP;
  int k = top_ks[b];
  if (k < 1) k = 1;
  if (k > V) k = V;

  for (int i = tid; i < cnt; i += 1024) {
    vals[i] = cvals[(size_t)b * CAP + i];
    idxs[i] = cidx[(size_t)b * CAP + i];
  }
  if (tid < 256) h2[tid] = 0u;
  if (tid == 0) s_kc = 0;
  __syncthreads();

  // refine: 8-bit hist of bits[19:12] within boundary 12-bit bin; count above
  const unsigned int tau12 = tau20[b] >> 8;
  int loc = 0;
  for (int i = tid; i < cnt; i += 1024) {
    unsigned int u = f2ord(vals[i]);
    unsigned int b12 = u >> 20;
    if (b12 > tau12) loc++;
    else if (b12 == tau12) atomicAdd(&h2[(u >> 12) & 255u], 1u);
  }
  rid[tid] = loc;
  __syncthreads();
  for (int s = 512; s > 0; s >>= 1) {
    if (tid < s) rid[tid] += rid[tid + s];
    __syncthreads();
  }
  const int cntGT = rid[0];
  if (tid == 0) {
    int need = k - cntGT;
    if (need < 1) need = 1;
    unsigned int run = 0;
    int sub = 255;
    for (; sub >= 0; --sub) {
      unsigned int hh = h2[sub];
      if (run + hh >= (unsigned int)need) break;
      run += hh;
    }
    if (sub < 0) sub = 0;
    s_sub = sub;
  }
  __syncthreads();
  const unsigned int tauf = (tau12 << 8) | (unsigned int)s_sub;  // 20-bit

  // compact kept (>= tauf) into sv/si
  for (int i = tid; i < cnt; i += 1024) {
    unsigned int u = f2ord(vals[i]);
    if ((u >> 12) >= tauf) {
      int p = atomicAdd(&s_kc, 1);
      sv[p] = vals[i];
      si[p] = idxs[i];
    }
  }
  __syncthreads();
  const int kc = s_kc;                       // >= k (superset of top-k)
  const int NP2 = (kc <= 1024) ? 1024 : 2048;
  for (int i = kc + tid; i < NP2; i += 1024) { sv[i] = -INFINITY; si[i] = 0x7fffffff; }
  __syncthreads();

  // bitonic sort over NP2: (val desc, idx asc)
  for (int size = 2; size <= NP2; size <<= 1) {
    for (int stride = size >> 1; stride > 0; stride >>= 1) {
      for (int i = tid; i < NP2; i += 1024) {
        int j = i ^ stride;
        if (j > i) {
          float vi = sv[i], vj = sv[j];
          int ii = si[i], ij = si[j];
          bool iBeforeJ = (vi > vj) || (vi == vj && ii < ij);
          bool up = ((i & size) == 0);
          if (up ? !iBeforeJ : iBeforeJ) {
            sv[i] = vj; si[i] = ij; sv[j] = vi; si[j] = ii;
          }
        }
      }
      __syncthreads();
    }
  }

  int K = (k < kc) ? k : kc;
  if (K > 1024) K = 1024;

  const float t = temps[b];
  const float tt = (t < 1e-5f) ? 1.0f : t;
  const float l0 = sv[0] / tt;
  ex[tid] = (tid < K) ? expf(sv[tid] / tt - l0) : 0.f;
  __syncthreads();

  rsc[tid] = ex[tid];
  __syncthreads();
  for (int s = 512; s > 0; s >>= 1) {
    if (tid < s) rsc[tid] += rsc[tid + s];
    __syncthreads();
  }
  if (tid == 0) s_S = rsc[0];
  __syncthreads();
  const float S = s_S;

  const float p = top_ps[b];
  int m;
  if (p >= 1.0f - 1e-5f) {
    m = K;
  } else {
    pr[tid] = ex[tid] / S;
    __syncthreads();
    for (int off = 1; off < 1024; off <<= 1) {
      float v = pr[tid] + ((tid >= off) ? pr[tid - off] : 0.f);
      __syncthreads();
      pr[tid] = v;
      __syncthreads();
    }
    rid[tid] = (tid < K && pr[tid] <= p) ? 1 : 0;
    __syncthreads();
    for (int s = 512; s > 0; s >>= 1) {
      if (tid < s) rid[tid] += rid[tid + s];
      __syncthreads();
    }
    if (tid == 0) s_m = (rid[0] < 1) ? 1 : rid[0];
    __syncthreads();
    m = s_m;
  }
  __syncthreads();

  rsc[tid] = (tid < m) ? ex[tid] : 0.f;
  __syncthreads();
  for (int s = 512; s > 0; s >>= 1) {
    if (tid < s) rsc[tid] += rsc[tid + s];
    __syncthreads();
  }
  if (tid == 0) s_S2 = rsc[0];
  __syncthreads();
  const float S2 = s_S2;

  for (int i = tid; i < m; i += 1024)
    out[(size_t)probs_base + (size_t)b * V + si[i]] = ex[i] / S2;

  float best = -INFINITY;
  int bestV = 0x7fffffff;
  for (int i = tid; i < m; i += 1024) {
    int vv = si[i];
    unsigned int flat = (unsigned int)b * (unsigned int)V + (unsigned int)vv;
    float g = gumbel_at(flat, half_n);
    float sc = sv[i] / tt + g;
    if (sc > best || (sc == best && vv < bestV)) { best = sc; bestV = vv; }
  }
  rsc[tid] = best; rid[tid] = bestV;
  __syncthreads();
  for (int s = 512; s > 0; s >>= 1) {
    if (tid < s) {
      float o = rsc[tid + s]; int oi = rid[tid + s];
      if (o > rsc[tid] || (o == rsc[tid] && oi < rid[tid])) { rsc[tid] = o; rid[tid] = oi; }
    }
    __syncthreads();
  }
  if (tid == 0) {
    int token = (t < 1e-5f) ? si[0] : rid[0];
    if (token < 0 || token >= V) token = 0;
    out[b] = (float)token;
  }
}

// ---------- launch ----------
extern "C" void kernel_launch(void* const* d_in, const int* in_sizes, int n_in,
                              void* d_out, int out_size, void* d_ws, size_t ws_size,
                              hipStream_t stream) {
  const float* hidden = (const float*)d_in[0];
  const float* emb    = (const float*)d_in[1];
  const int*   lti    = (const int*)d_in[2];
  const float* temps  = (const float*)d_in[3];
  const float* tops   = (const float*)d_in[4];
  const int*   topks  = (const int*)d_in[5];

  const int B = in_sizes[2];
  const int V = (int)(((long long)out_size - B) / B);
  const int D = in_sizes[1] / V;
  const int probs_base = out_size - B * V;  // = B
  const unsigned int half_n = (unsigned int)(((long long)B * V) / 2);

  float* out = (float*)d_out;

  char* ws = (char*)d_ws;
  size_t off = 0;
  unsigned short* Ah = (unsigned short*)(ws + off); off += (size_t)B * D * sizeof(unsigned short);
  unsigned short* Al = (unsigned short*)(ws + off); off += (size_t)B * D * sizeof(unsigned short);
  float* cvals = (float*)(ws + off); off += (size_t)B * CAP * sizeof(float);
  int* cidx = (int*)(ws + off);      off += (size_t)B * CAP * sizeof(int);
  int* ccnt = (int*)(ws + off);      off += (size_t)B * sizeof(int);
  unsigned int* gslices = (unsigned int*)(ws + off); off += (size_t)B * 8 * 4096 * sizeof(unsigned int);
  unsigned int* tau_out = (unsigned int*)(ws + off); off += (size_t)B * sizeof(unsigned int);
  (void)ws_size; (void)n_in;

  float* logits = out + probs_base;

  hipLaunchKernelGGL(gather_split, dim3(B), dim3(256), 0, stream, hidden, lti, Ah, Al, D);
  hipLaunchKernelGGL(gemm_mfma, dim3(V / BN), dim3(256), 0, stream, Ah, Al, emb, logits, D, V);
  hipLaunchKernelGGL(hist_k, dim3(8 * B), dim3(256), 0, stream, logits, gslices, ccnt, V);
  hipLaunchKernelGGL(gather_k, dim3(8 * B), dim3(256), 0, stream, logits, gslices, topks,
                     cvals, cidx, ccnt, tau_out, V);
  hipLaunchKernelGGL(finalize_k, dim3(B), dim3(1024), 0, stream, cvals, cidx, ccnt, tau_out,
                     topks, temps, tops, out, probs_base, V, half_n);
}